// Round 4
// baseline (10042.060 us; speedup 1.0000x reference)
//
#include <hip/hip_runtime.h>
#include <stdint.h>
#include <math.h>

// Problem constants (match reference)
#define BB 128
#define NN 2048
#define DD 2
#define ROWLEN (2 + NN * DD + 5)   // 4103
#define SIGMA_C 0.001f
#define HALF_CNT 262144u           // B*N*D / 2

// SSA vector types for small register-resident layers (no allocas).
typedef float v16f __attribute__((ext_vector_type(16)));
typedef float v32f __attribute__((ext_vector_type(32)));

// elu derivative from elu output: d = (z>0) ? 1 : exp(z); for z<=0,
// h = exp(z)-1  =>  d = h+1 (<=1 ulp difference). h>0 <=> z>0 (monotone).
#define DFROMH(h) ((h) > 0.0f ? 1.0f : (h) + 1.0f)

__device__ __forceinline__ uint32_t rotl32(uint32_t v, uint32_t r) {
  return (v << r) | (v >> (32u - r));
}

// JAX threefry2x32 (20 rounds), matches jax/_src/prng.py
__device__ __forceinline__ void tf2x32(uint32_t k0, uint32_t k1,
                                       uint32_t x0, uint32_t x1,
                                       uint32_t& o0, uint32_t& o1) {
  uint32_t k2 = k0 ^ k1 ^ 0x1BD11BDAu;
  x0 += k0; x1 += k1;
#define TF_R(r) { x0 += x1; x1 = rotl32(x1, r); x1 ^= x0; }
  TF_R(13) TF_R(15) TF_R(26) TF_R(6)   x0 += k1; x1 += k2 + 1u;
  TF_R(17) TF_R(29) TF_R(16) TF_R(24)  x0 += k2; x1 += k0 + 2u;
  TF_R(13) TF_R(15) TF_R(26) TF_R(6)   x0 += k0; x1 += k1 + 3u;
  TF_R(17) TF_R(29) TF_R(16) TF_R(24)  x0 += k1; x1 += k2 + 4u;
  TF_R(13) TF_R(15) TF_R(26) TF_R(6)   x0 += k2; x1 += k0 + 5u;
#undef TF_R
  o0 = x0; o1 = x1;
}

// XLA f32 ErfInv (Giles 2012 polynomial) — what lax.erf_inv lowers to
__device__ __forceinline__ float erfinv_f32(float x) {
  float w = -log1pf(-(x * x));
  float p;
  if (w < 5.0f) {
    w = w - 2.5f;
    p = 2.81022636e-08f;
    p = fmaf(p, w, 3.43273939e-07f);
    p = fmaf(p, w, -3.5233877e-06f);
    p = fmaf(p, w, -4.39150654e-06f);
    p = fmaf(p, w, 0.00021858087f);
    p = fmaf(p, w, -0.00125372503f);
    p = fmaf(p, w, -0.00417768164f);
    p = fmaf(p, w, 0.246640727f);
    p = fmaf(p, w, 1.50140941f);
  } else {
    w = sqrtf(w) - 3.0f;
    p = -0.000200214257f;
    p = fmaf(p, w, 0.000100950558f);
    p = fmaf(p, w, 0.00134934322f);
    p = fmaf(p, w, -0.00367342844f);
    p = fmaf(p, w, 0.00573950773f);
    p = fmaf(p, w, -0.0076224613f);
    p = fmaf(p, w, 0.00943887047f);
    p = fmaf(p, w, 1.00167406f);
    p = fmaf(p, w, 2.83297682f);
  }
  return p * x;
}

// jax.random.normal for one flat element index f under key (k0,k1)
__device__ __forceinline__ float jax_normal_elem(uint32_t k0, uint32_t k1,
                                                 uint32_t f) {
  uint32_t o0, o1, bits;
  if (f < HALF_CNT) {
    tf2x32(k0, k1, f, f + HALF_CNT, o0, o1);
    bits = o0;
  } else {
    tf2x32(k0, k1, f - HALF_CNT, f, o0, o1);
    bits = o1;
  }
  float u01 = __uint_as_float((bits >> 9) | 0x3f800000u) - 1.0f;
  const float lo = -0.99999994f;           // nextafter(-1, 0) in f32
  float v = fmaxf(lo, fmaf(u01, 2.0f, lo));
  return 1.41421356237309515f * erfinv_f32(v);
}

// LDS stash for the wide activations (h2, h3): 64 floats/thread.
// R3 showed keeping all of h1..h4 + transients in registers exceeds what the
// allocator will give (~84 VGPRs) -> scratch spills -> 25-60 MB working set
// thrashes L2 -> the per-step weight stream (17 KB/wave) misses to HBM
// (2.1 GB FETCH). Moving h2/h3 to LDS caps register peak at ~90 and keeps L2
// clean for weights. Layout [unit][tid]: lane-consecutive -> 2-way bank
// aliasing only (free). Each thread reads only its own column: no barriers.
#define LDS_FLOATS (64 * 256)   // 64 KB

__global__ __launch_bounds__(256, 2) void phinn_kernel(
    const float* __restrict__ x,
    const float* __restrict__ W1, const float* __restrict__ b1,
    const float* __restrict__ W2, const float* __restrict__ b2,
    const float* __restrict__ W3, const float* __restrict__ b3,
    const float* __restrict__ W4, const float* __restrict__ b4,
    const float* __restrict__ W5, const float* __restrict__ b5,
    const float* __restrict__ Wt,
    const float* __restrict__ dtp, const int* __restrict__ nstepsp,
    float* __restrict__ out) {
  __shared__ float sh[LDS_FLOATS];   // [0..31]=h2, [32..63]=h3, stride 256

  const int tx = threadIdx.x;
  const int tid = blockIdx.x * 256 + tx;   // 0 .. B*N-1
  const int bidx = tid >> 11;               // / N
  const int nidx = tid & (NN - 1);

  const float dt = dtp[0];
  const int nsteps = nstepsp[0];
  const float sqdt = sqrtf(dt);

  const float* xr = x + (size_t)bidx * ROWLEN;
  float t = xr[0];
  float y0 = xr[2 + nidx * 2 + 0];
  float y1 = xr[2 + nidx * 2 + 1];
  const float tcrit = xr[2 + NN * DD + 0];
  const float sp0 = xr[2 + NN * DD + 1];
  const float sp1 = xr[2 + NN * DD + 2];
  const float sq0 = xr[2 + NN * DD + 3];
  const float sq1 = xr[2 + NN * DD + 4];

  // Wt is (D, NSIG) row-major; tilt[d] = sum_s signals[s] * Wt[d][s]
  const float wt00 = Wt[0], wt01 = Wt[1], wt10 = Wt[2], wt11 = Wt[3];

  const uint32_t f0 = (uint32_t)(tid << 1);  // flat idx of component 0

#pragma unroll 1
  for (int i = 0; i < nsteps; ++i) {
    // per-step key: fold_in(key(42), i) = threefry((0,42), (0,i))
    // i is uniform -> SALU
    uint32_t k0, k1;
    tf2x32(0u, 42u, 0u, (uint32_t)i, k0, k1);

    // ---- forward: 2 -> 16 -> 32 -> 32 -> 16 -> 1 ----
    v16f h1;   // registers (needed for d1 in backward)
#pragma unroll
    for (int j = 0; j < 16; ++j) {
      float z = fmaf(W1[2 * j + 0], y0, fmaf(W1[2 * j + 1], y1, b1[j]));
      h1[j] = z > 0.0f ? z : (__expf(z) - 1.0f);
    }
    {
      v32f h2r;  // transient regs; stashed to LDS for backward
#pragma unroll
      for (int j = 0; j < 32; ++j) {
        float z = b2[j];
#pragma unroll
        for (int k = 0; k < 16; ++k) z = fmaf(W2[16 * j + k], h1[k], z);
        float h = z > 0.0f ? z : (__expf(z) - 1.0f);
        h2r[j] = h;
        sh[j * 256 + tx] = h;
      }
      v32f h3r;
#pragma unroll
      for (int j = 0; j < 32; ++j) {
        float z = b3[j];
#pragma unroll
        for (int k = 0; k < 32; ++k) z = fmaf(W3[32 * j + k], h2r[k], z);
        float h = z > 0.0f ? z : (__expf(z) - 1.0f);
        h3r[j] = h;
        sh[(32 + j) * 256 + tx] = h;
      }
      // h2r dead here; h4 from h3r
      v16f h4;
#pragma unroll
      for (int j = 0; j < 16; ++j) {
        float z = b4[j];
#pragma unroll
        for (int k = 0; k < 32; ++k) z = fmaf(W4[32 * j + k], h3r[k], z);
        h4[j] = z > 0.0f ? z : (__expf(z) - 1.0f);
      }
      float z5 = b5[0];
#pragma unroll
      for (int k = 0; k < 16; ++k) z5 = fmaf(W5[k], h4[k], z5);
      float g5 = 1.0f / (1.0f + __expf(-z5));  // d softplus = sigmoid

      // ---- backward (input-gradient) ----
      v16f g4;
#pragma unroll
      for (int k = 0; k < 16; ++k) g4[k] = W5[k] * g5 * DFROMH(h4[k]);

      v32f g3;
#pragma unroll
      for (int k = 0; k < 32; ++k) {
        float s = 0.0f;
#pragma unroll
        for (int j = 0; j < 16; ++j) s = fmaf(W4[32 * j + k], g4[j], s);
        g3[k] = s * DFROMH(sh[(32 + k) * 256 + tx]);
      }
      v32f g2;
#pragma unroll
      for (int k = 0; k < 32; ++k) {
        float s = 0.0f;
#pragma unroll
        for (int j = 0; j < 32; ++j) s = fmaf(W3[32 * j + k], g3[j], s);
        g2[k] = s * DFROMH(sh[k * 256 + tx]);
      }
      v16f g1;
#pragma unroll
      for (int k = 0; k < 16; ++k) {
        float s = 0.0f;
#pragma unroll
        for (int j = 0; j < 32; ++j) s = fmaf(W2[16 * j + k], g2[j], s);
        g1[k] = s * DFROMH(h1[k]);
      }
      float gy0 = 0.0f, gy1 = 0.0f;
#pragma unroll
      for (int j = 0; j < 16; ++j) {
        gy0 = fmaf(W1[2 * j + 0], g1[j], gy0);
        gy1 = fmaf(W1[2 * j + 1], g1[j], gy1);
      }

      // ---- tilt ----
      bool pre = t < tcrit;
      float s0 = pre ? sp0 : sq0;
      float s1 = pre ? sp1 : sq1;
      float tilt0 = fmaf(s0, wt00, s1 * wt01);
      float tilt1 = fmaf(s0, wt10, s1 * wt11);

      // ---- noise (exact JAX threefry normal) ----
      float nz0 = jax_normal_elem(k0, k1, f0);
      float nz1 = jax_normal_elem(k0, k1, f0 + 1u);

      // ---- Euler-Maruyama update ----
      float drift0 = -(gy0 + tilt0);
      float drift1 = -(gy1 + tilt1);
      y0 = y0 + drift0 * dt + SIGMA_C * (nz0 * sqdt);
      y1 = y1 + drift1 * dt + SIGMA_C * (nz1 * sqdt);
      t += dt;
    }
  }

  out[(size_t)tid * 2 + 0] = y0;
  out[(size_t)tid * 2 + 1] = y1;
}

extern "C" void kernel_launch(void* const* d_in, const int* in_sizes, int n_in,
                              void* d_out, int out_size, void* d_ws,
                              size_t ws_size, hipStream_t stream) {
  const float* x  = (const float*)d_in[0];
  const float* W1 = (const float*)d_in[1];
  const float* b1 = (const float*)d_in[2];
  const float* W2 = (const float*)d_in[3];
  const float* b2 = (const float*)d_in[4];
  const float* W3 = (const float*)d_in[5];
  const float* b3 = (const float*)d_in[6];
  const float* W4 = (const float*)d_in[7];
  const float* b4 = (const float*)d_in[8];
  const float* W5 = (const float*)d_in[9];
  const float* b5 = (const float*)d_in[10];
  const float* Wt = (const float*)d_in[11];
  const float* dt = (const float*)d_in[12];
  const int* nsteps = (const int*)d_in[13];
  float* out = (float*)d_out;

  dim3 grid((BB * NN) / 256);
  dim3 block(256);
  hipLaunchKernelGGL(phinn_kernel, grid, block, 0, stream,
                     x, W1, b1, W2, b2, W3, b3, W4, b4, W5, b5, Wt, dt, nsteps,
                     out);
}

// Round 5
// 9969.295 us; speedup vs baseline: 1.0073x; 1.0073x over previous
//
#include <hip/hip_runtime.h>
#include <stdint.h>
#include <math.h>

// Problem constants (match reference)
#define BB 128
#define NN 2048
#define DD 2
#define ROWLEN (2 + NN * DD + 5)   // 4103
#define SIGMA_C 0.001f
#define HALF_CNT 262144u           // B*N*D / 2

// SSA vector types for small register-resident layers (no allocas).
typedef float v16f __attribute__((ext_vector_type(16)));
typedef float v32f __attribute__((ext_vector_type(32)));

// elu derivative from elu output: d = (z>0) ? 1 : exp(z); for z<=0,
// h = exp(z)-1  =>  d = h+1 (<=1 ulp difference). h>0 <=> z>0 (monotone).
#define DFROMH(h) ((h) > 0.0f ? 1.0f : (h) + 1.0f)

__device__ __forceinline__ uint32_t rotl32(uint32_t v, uint32_t r) {
  return (v << r) | (v >> (32u - r));
}

// JAX threefry2x32 (20 rounds), matches jax/_src/prng.py
__device__ __forceinline__ void tf2x32(uint32_t k0, uint32_t k1,
                                       uint32_t x0, uint32_t x1,
                                       uint32_t& o0, uint32_t& o1) {
  uint32_t k2 = k0 ^ k1 ^ 0x1BD11BDAu;
  x0 += k0; x1 += k1;
#define TF_R(r) { x0 += x1; x1 = rotl32(x1, r); x1 ^= x0; }
  TF_R(13) TF_R(15) TF_R(26) TF_R(6)   x0 += k1; x1 += k2 + 1u;
  TF_R(17) TF_R(29) TF_R(16) TF_R(24)  x0 += k2; x1 += k0 + 2u;
  TF_R(13) TF_R(15) TF_R(26) TF_R(6)   x0 += k0; x1 += k1 + 3u;
  TF_R(17) TF_R(29) TF_R(16) TF_R(24)  x0 += k1; x1 += k2 + 4u;
  TF_R(13) TF_R(15) TF_R(26) TF_R(6)   x0 += k2; x1 += k0 + 5u;
#undef TF_R
  o0 = x0; o1 = x1;
}

// XLA f32 ErfInv (Giles 2012 polynomial) — what lax.erf_inv lowers to
__device__ __forceinline__ float erfinv_f32(float x) {
  float w = -log1pf(-(x * x));
  float p;
  if (w < 5.0f) {
    w = w - 2.5f;
    p = 2.81022636e-08f;
    p = fmaf(p, w, 3.43273939e-07f);
    p = fmaf(p, w, -3.5233877e-06f);
    p = fmaf(p, w, -4.39150654e-06f);
    p = fmaf(p, w, 0.00021858087f);
    p = fmaf(p, w, -0.00125372503f);
    p = fmaf(p, w, -0.00417768164f);
    p = fmaf(p, w, 0.246640727f);
    p = fmaf(p, w, 1.50140941f);
  } else {
    w = sqrtf(w) - 3.0f;
    p = -0.000200214257f;
    p = fmaf(p, w, 0.000100950558f);
    p = fmaf(p, w, 0.00134934322f);
    p = fmaf(p, w, -0.00367342844f);
    p = fmaf(p, w, 0.00573950773f);
    p = fmaf(p, w, -0.0076224613f);
    p = fmaf(p, w, 0.00943887047f);
    p = fmaf(p, w, 1.00167406f);
    p = fmaf(p, w, 2.83297682f);
  }
  return p * x;
}

// jax.random.normal for one flat element index f under key (k0,k1)
__device__ __forceinline__ float jax_normal_elem(uint32_t k0, uint32_t k1,
                                                 uint32_t f) {
  uint32_t o0, o1, bits;
  if (f < HALF_CNT) {
    tf2x32(k0, k1, f, f + HALF_CNT, o0, o1);
    bits = o0;
  } else {
    tf2x32(k0, k1, f - HALF_CNT, f, o0, o1);
    bits = o1;
  }
  float u01 = __uint_as_float((bits >> 9) | 0x3f800000u) - 1.0f;
  const float lo = -0.99999994f;           // nextafter(-1, 0) in f32
  float v = fmaxf(lo, fmaf(u01, 2.0f, lo));
  return 1.41421356237309515f * erfinv_f32(v);
}

// LDS stash for the wide fwd->bwd activations (h2, h3): 64 floats/thread.
// Layout [unit][tid]: lane-consecutive -> 2-way bank aliasing (free, m136).
// Each thread touches only its own column: no barriers needed.
#define LDS_FLOATS (64 * 256)   // 64 KB -> 2 blocks/CU -> 2 waves/EU

// amdgpu_waves_per_eu(2,2): pins the GCN scheduler's occupancy target AND
// the RA budget to 2 waves/EU = 256 VGPRs. History:
//   R2: this attr + alloca arrays -> no-op (arrays never register candidates)
//   R3/R4: SSA vectors + __launch_bounds__(256,2) -> 2nd arg is only a MIN;
//     scheduler chased ~5-6 waves/EU and spilled at ~96 VGPRs
//     (WRITE_SIZE 181 MB of scratch, FETCH 870 MB of L2-thrash misses).
// This round: SSA vectors + pinned (2,2) — live set ~110 regs, budget 256.
__global__ __attribute__((amdgpu_flat_work_group_size(256, 256),
                          amdgpu_waves_per_eu(2, 2)))
void phinn_kernel(
    const float* __restrict__ x,
    const float* __restrict__ W1, const float* __restrict__ b1,
    const float* __restrict__ W2, const float* __restrict__ b2,
    const float* __restrict__ W3, const float* __restrict__ b3,
    const float* __restrict__ W4, const float* __restrict__ b4,
    const float* __restrict__ W5, const float* __restrict__ b5,
    const float* __restrict__ Wt,
    const float* __restrict__ dtp, const int* __restrict__ nstepsp,
    float* __restrict__ out) {
  __shared__ float sh[LDS_FLOATS];   // [0..31]=h2, [32..63]=h3, stride 256

  const int tx = threadIdx.x;
  const int tid = blockIdx.x * 256 + tx;   // 0 .. B*N-1
  const int bidx = tid >> 11;               // / N
  const int nidx = tid & (NN - 1);

  const float dt = dtp[0];
  const int nsteps = nstepsp[0];
  const float sqdt = sqrtf(dt);

  const float* xr = x + (size_t)bidx * ROWLEN;
  float t = xr[0];
  float y0 = xr[2 + nidx * 2 + 0];
  float y1 = xr[2 + nidx * 2 + 1];
  const float tcrit = xr[2 + NN * DD + 0];
  const float sp0 = xr[2 + NN * DD + 1];
  const float sp1 = xr[2 + NN * DD + 2];
  const float sq0 = xr[2 + NN * DD + 3];
  const float sq1 = xr[2 + NN * DD + 4];

  // Wt is (D, NSIG) row-major; tilt[d] = sum_s signals[s] * Wt[d][s]
  const float wt00 = Wt[0], wt01 = Wt[1], wt10 = Wt[2], wt11 = Wt[3];

  const uint32_t f0 = (uint32_t)(tid << 1);  // flat idx of component 0

#pragma unroll 1
  for (int i = 0; i < nsteps; ++i) {
    // per-step key: fold_in(key(42), i) = threefry((0,42), (0,i))
    // i is uniform -> SALU
    uint32_t k0, k1;
    tf2x32(0u, 42u, 0u, (uint32_t)i, k0, k1);

    // ---- forward: 2 -> 16 -> 32 -> 32 -> 16 -> 1 ----
    v16f h1;   // registers (needed for d1 in backward)
#pragma unroll
    for (int j = 0; j < 16; ++j) {
      float z = fmaf(W1[2 * j + 0], y0, fmaf(W1[2 * j + 1], y1, b1[j]));
      h1[j] = z > 0.0f ? z : (__expf(z) - 1.0f);
    }
    {
      v32f h2r;  // transient regs; stashed to LDS for backward
#pragma unroll
      for (int j = 0; j < 32; ++j) {
        float z = b2[j];
#pragma unroll
        for (int k = 0; k < 16; ++k) z = fmaf(W2[16 * j + k], h1[k], z);
        float h = z > 0.0f ? z : (__expf(z) - 1.0f);
        h2r[j] = h;
        sh[j * 256 + tx] = h;
      }
      v32f h3r;
#pragma unroll
      for (int j = 0; j < 32; ++j) {
        float z = b3[j];
#pragma unroll
        for (int k = 0; k < 32; ++k) z = fmaf(W3[32 * j + k], h2r[k], z);
        float h = z > 0.0f ? z : (__expf(z) - 1.0f);
        h3r[j] = h;
        sh[(32 + j) * 256 + tx] = h;
      }
      // h2r dead here; h4 from h3r
      v16f h4;
#pragma unroll
      for (int j = 0; j < 16; ++j) {
        float z = b4[j];
#pragma unroll
        for (int k = 0; k < 32; ++k) z = fmaf(W4[32 * j + k], h3r[k], z);
        h4[j] = z > 0.0f ? z : (__expf(z) - 1.0f);
      }
      float z5 = b5[0];
#pragma unroll
      for (int k = 0; k < 16; ++k) z5 = fmaf(W5[k], h4[k], z5);
      float g5 = 1.0f / (1.0f + __expf(-z5));  // d softplus = sigmoid

      // ---- backward (input-gradient) ----
      v16f g4;
#pragma unroll
      for (int k = 0; k < 16; ++k) g4[k] = W5[k] * g5 * DFROMH(h4[k]);

      v32f g3;
#pragma unroll
      for (int k = 0; k < 32; ++k) {
        float s = 0.0f;
#pragma unroll
        for (int j = 0; j < 16; ++j) s = fmaf(W4[32 * j + k], g4[j], s);
        g3[k] = s * DFROMH(sh[(32 + k) * 256 + tx]);
      }
      v32f g2;
#pragma unroll
      for (int k = 0; k < 32; ++k) {
        float s = 0.0f;
#pragma unroll
        for (int j = 0; j < 32; ++j) s = fmaf(W3[32 * j + k], g3[j], s);
        g2[k] = s * DFROMH(sh[k * 256 + tx]);
      }
      v16f g1;
#pragma unroll
      for (int k = 0; k < 16; ++k) {
        float s = 0.0f;
#pragma unroll
        for (int j = 0; j < 32; ++j) s = fmaf(W2[16 * j + k], g2[j], s);
        g1[k] = s * DFROMH(h1[k]);
      }
      float gy0 = 0.0f, gy1 = 0.0f;
#pragma unroll
      for (int j = 0; j < 16; ++j) {
        gy0 = fmaf(W1[2 * j + 0], g1[j], gy0);
        gy1 = fmaf(W1[2 * j + 1], g1[j], gy1);
      }

      // ---- tilt ----
      bool pre = t < tcrit;
      float s0 = pre ? sp0 : sq0;
      float s1 = pre ? sp1 : sq1;
      float tilt0 = fmaf(s0, wt00, s1 * wt01);
      float tilt1 = fmaf(s0, wt10, s1 * wt11);

      // ---- noise (exact JAX threefry normal) ----
      float nz0 = jax_normal_elem(k0, k1, f0);
      float nz1 = jax_normal_elem(k0, k1, f0 + 1u);

      // ---- Euler-Maruyama update ----
      float drift0 = -(gy0 + tilt0);
      float drift1 = -(gy1 + tilt1);
      y0 = y0 + drift0 * dt + SIGMA_C * (nz0 * sqdt);
      y1 = y1 + drift1 * dt + SIGMA_C * (nz1 * sqdt);
      t += dt;
    }
  }

  out[(size_t)tid * 2 + 0] = y0;
  out[(size_t)tid * 2 + 1] = y1;
}

extern "C" void kernel_launch(void* const* d_in, const int* in_sizes, int n_in,
                              void* d_out, int out_size, void* d_ws,
                              size_t ws_size, hipStream_t stream) {
  const float* x  = (const float*)d_in[0];
  const float* W1 = (const float*)d_in[1];
  const float* b1 = (const float*)d_in[2];
  const float* W2 = (const float*)d_in[3];
  const float* b2 = (const float*)d_in[4];
  const float* W3 = (const float*)d_in[5];
  const float* b3 = (const float*)d_in[6];
  const float* W4 = (const float*)d_in[7];
  const float* b4 = (const float*)d_in[8];
  const float* W5 = (const float*)d_in[9];
  const float* b5 = (const float*)d_in[10];
  const float* Wt = (const float*)d_in[11];
  const float* dt = (const float*)d_in[12];
  const int* nsteps = (const int*)d_in[13];
  float* out = (float*)d_out;

  dim3 grid((BB * NN) / 256);
  dim3 block(256);
  hipLaunchKernelGGL(phinn_kernel, grid, block, 0, stream,
                     x, W1, b1, W2, b2, W3, b3, W4, b4, W5, b5, Wt, dt, nsteps,
                     out);
}